// Round 5
// baseline (344.290 us; speedup 1.0000x reference)
//
#include <hip/hip_runtime.h>
#include <cstdint>

// Problem constants: N=8192, T=1024, CD=4, H=2, KD=VD=8, DA=8, AOD=16, LAT=64, OUT=32.
//
// Spill history (measured): R1 (256,4) VGPR64 + 33MB scratch; R2 (256,5)
// VGPR48 + 220MB; R3 (none) VGPR64 + 425MB; R4 (waves_per_eu 4,5) VGPR64 +
// 258MB. The allocator pins 64 VGPR regardless of declared bounds. So:
// DESIGN for 64 VGPR — half-wave head split (p[16] -> 8 named scalars/lane),
// no max-subtraction (logits bounded, masked e underflow to exact 0), no
// online rescale. Peak live ~45 regs.

__device__ __forceinline__ float bflo(uint32_t u) { return __uint_as_float(u << 16); }
__device__ __forceinline__ float bfhi(uint32_t u) { return __uint_as_float(u & 0xFFFF0000u); }
__device__ __forceinline__ uint32_t f2bf(float f) {
    uint32_t x = __float_as_uint(f);
    return (x + 0x7FFFu + ((x >> 16) & 1u)) >> 16;   // RNE
}
__device__ __forceinline__ float ftanh(float x) {
    float e = __expf(2.0f * x);
    return 1.0f - 2.0f / (e + 1.0f);   // stable for +-inf of e
}

__global__ __launch_bounds__(256, 4)
void attn_mlp_fused(const float* __restrict__ coord1,
                    const float* __restrict__ coord2,
                    const float* __restrict__ att_coeff,
                    const float* __restrict__ local_coords,
                    const void*  __restrict__ maskp,
                    const float* __restrict__ Wq, const float* __restrict__ Bq,
                    const float* __restrict__ Wk, const float* __restrict__ Bk,
                    const float* __restrict__ Wv, const float* __restrict__ Bv,
                    const float* __restrict__ Wo, const float* __restrict__ Bo,
                    const float* __restrict__ W1, const float* __restrict__ B1,
                    const float* __restrict__ W2, const float* __restrict__ B2,
                    const float* __restrict__ Wt, const float* __restrict__ Bt,
                    float* __restrict__ out)
{
    __shared__ uint4 vq[2048];                 // v table, bf16x2 packed, swizzled (exactly 32 KB)

    const int tid  = threadIdx.x;
    const int lane = tid & 63;
    const int wid  = tid >> 6;

    // ---- detect mask element size: 4-byte (int/float 0/1) vs 1-byte (bool) ----
    uint4 mm = ((const uint4*)maskp)[tid];
    bool ok = (mm.x <= 1u || mm.x == 0x3F800000u) &&
              (mm.y <= 1u || mm.y == 0x3F800000u) &&
              (mm.z <= 1u || mm.z == 0x3F800000u) &&
              (mm.w <= 1u || mm.w == 0x3F800000u);
    const bool m4 = (__all(ok) != 0);

    // ---- stage v = att_coeff @ Wv + Bv into LDS (bf16x2, XOR-swizzled) ----
    #pragma unroll
    for (int tt = 0; tt < 4; ++tt) {
        const int t = tid * 4 + tt;
        const float4 a0 = *(const float4*)(att_coeff + t * 8);
        const float4 a1 = *(const float4*)(att_coeff + t * 8 + 4);
        float vr[16];
        #pragma unroll
        for (int o = 0; o < 16; ++o) {
            vr[o] = Bv[o]
                + a0.x * Wv[o]      + a0.y * Wv[16 + o] + a0.z * Wv[32 + o] + a0.w * Wv[48 + o]
                + a1.x * Wv[64 + o] + a1.y * Wv[80 + o] + a1.z * Wv[96 + o] + a1.w * Wv[112 + o];
        }
        #pragma unroll
        for (int h = 0; h < 2; ++h) {
            const int g  = 2 * t + h;
            const int gs = (g & ~7) | ((g ^ (g >> 3)) & 7);
            uint4 pk;
            pk.x = f2bf(vr[h * 8 + 0]) | (f2bf(vr[h * 8 + 1]) << 16);
            pk.y = f2bf(vr[h * 8 + 2]) | (f2bf(vr[h * 8 + 3]) << 16);
            pk.z = f2bf(vr[h * 8 + 4]) | (f2bf(vr[h * 8 + 5]) << 16);
            pk.w = f2bf(vr[h * 8 + 6]) | (f2bf(vr[h * 8 + 7]) << 16);
            vq[gs] = pk;
        }
    }
    __syncthreads();

    const int l  = lane & 31;          // t-slot within half-wave
    const int hb = (lane >> 5) * 8;    // own head base (0 or 8)

    // v-table base group for (t = l + 32*i, own head): g0 = 2*l + h
    const int g0 = 2 * l + (lane >> 5);
    const int bg = (g0 & ~7) | ((g0 ^ (g0 >> 3)) & 7);   // vq[bg + 64*i]

    const float rs8 = 0.35355339059327373f;   // 1/sqrt(KD)

    const uint32_t msh   = m4 ? 0u : ((l & 3) * 8);
    const uint32_t mmsk  = m4 ? 0xFFFFFFFFu : 0xFFu;
    const int      mstep = m4 ? 32 : 8;

    #pragma unroll 1   // two rows must NOT interleave (register pressure)
    for (int it = 0; it < 2; ++it) {
        const int n = (blockIdx.x << 3) + (it << 2) + wid;

        const float4 c1 = *(const float4*)(coord1 + n * 4);
        const float4 c2 = *(const float4*)(coord2 + n * 4);

        // own-head q -> folded A[4], Bs (q dead after)
        float A0, A1, A2, A3, Bsv;
        {
            float qd[8];
            #pragma unroll
            for (int d = 0; d < 8; ++d)
                qd[d] = Bq[hb + d]
                      + c1.x * Wq[0 * 16 + hb + d] + c1.y * Wq[1 * 16 + hb + d]
                      + c1.z * Wq[2 * 16 + hb + d] + c1.w * Wq[3 * 16 + hb + d];
            float a[4];
            #pragma unroll
            for (int c = 0; c < 4; ++c) {
                float s = 0.f;
                #pragma unroll
                for (int d = 0; d < 8; ++d) s += qd[d] * Wk[c * 16 + hb + d];
                a[c] = s * rs8;
            }
            float s2 = 0.f;
            #pragma unroll
            for (int d = 0; d < 8; ++d) s2 += qd[d] * Bk[hb + d];
            A0 = a[0]; A1 = a[1]; A2 = a[2]; A3 = a[3]; Bsv = s2 * rs8;
        }

        // ---- one pass over own head's T-slice: t = l + 32*i ----
        const float4*   lcp = (const float4*)local_coords + (size_t)n * 1024 + l;
        const uint32_t* mp  = (const uint32_t*)maskp +
                              (m4 ? ((size_t)n * 1024 + l)
                                  : ((size_t)n * 256 + (l >> 2)));

        float p0 = 0.f, p1 = 0.f, p2 = 0.f, p3 = 0.f;
        float p4 = 0.f, p5 = 0.f, p6 = 0.f, p7 = 0.f;
        float s0 = 0.f;

        #pragma unroll 2
        for (int i = 0; i < 32; ++i) {
            const float4   lc = lcp[i * 32];
            const uint32_t mw = mp[i * mstep];
            const bool keep = ((mw >> msh) & mmsk) != 0u;
            const float v = Bsv + lc.x * A0 + lc.y * A1 + lc.z * A2 + lc.w * A3;
            const float e = keep ? __expf(v) : 0.f;   // |v| small by construction: no overflow
            s0 += e;
            const uint4 w = vq[bg + (i << 6)];
            p0 += e * bflo(w.x); p1 += e * bfhi(w.x);
            p2 += e * bflo(w.y); p3 += e * bfhi(w.y);
            p4 += e * bflo(w.z); p5 += e * bfhi(w.z);
            p6 += e * bflo(w.w); p7 += e * bfhi(w.w);
        }

        // head-total sum across the half-wave (xor<32 stays within half)
        #pragma unroll
        for (int s = 16; s; s >>= 1) s0 += __shfl_xor(s0, s, 64);

        // all-masked fallback: reference softmax(-1e30 row) = uniform over T
        if (s0 == 0.0f) {
            #pragma unroll 2
            for (int i = 0; i < 32; ++i) {
                const uint4 w = vq[bg + (i << 6)];
                p0 += bflo(w.x); p1 += bfhi(w.x);
                p2 += bflo(w.y); p3 += bfhi(w.y);
                p4 += bflo(w.z); p5 += bfhi(w.z);
                p6 += bflo(w.w); p7 += bfhi(w.w);
            }
            s0 = 1024.0f;
        }

        // ---- split butterfly within half-wave: lane ends with elem (lane>>2)&7 ----
        {
            const bool b = (lane & 16) != 0;
            const float n0 = (b ? p4 : p0) + __shfl_xor(b ? p0 : p4, 16, 64);
            const float n1 = (b ? p5 : p1) + __shfl_xor(b ? p1 : p5, 16, 64);
            const float n2 = (b ? p6 : p2) + __shfl_xor(b ? p2 : p6, 16, 64);
            const float n3 = (b ? p7 : p3) + __shfl_xor(b ? p3 : p7, 16, 64);
            p0 = n0; p1 = n1; p2 = n2; p3 = n3;
        }
        {
            const bool b = (lane & 8) != 0;
            const float n0 = (b ? p2 : p0) + __shfl_xor(b ? p0 : p2, 8, 64);
            const float n1 = (b ? p3 : p1) + __shfl_xor(b ? p1 : p3, 8, 64);
            p0 = n0; p1 = n1;
        }
        {
            const bool b = (lane & 4) != 0;
            p0 = (b ? p1 : p0) + __shfl_xor(b ? p0 : p1, 4, 64);
        }
        p0 += __shfl_xor(p0, 2, 64);
        p0 += __shfl_xor(p0, 1, 64);

        // every lane: attn[(lane>>2)&7] of head lane>>5
        const float pn = p0 / s0;

        // ---- att[j] = exp(-(attn . Wo[:,j] + Bo[j])), j = lane&15 ----
        // attn[c] (c = h*8+e) lives at lane 32*(c>>3) + 4*(c&7)
        float attv;
        {
            const int j = lane & 15;
            float acc = Bo[j];
            #pragma unroll
            for (int c = 0; c < 16; ++c)
                acc += __shfl(pn, ((c & 7) << 2) | ((c >> 3) << 5), 64) * Wo[c * 16 + j];
            attv = __expf(-acc);
        }

        // ---- layer 1: act1[lane] = tanh([c1,c2,att] . W1[:,lane] + B1[lane]) ----
        float a1;
        {
            float acc = B1[lane];
            acc += c1.x * W1[0 * 64 + lane] + c1.y * W1[1 * 64 + lane]
                 + c1.z * W1[2 * 64 + lane] + c1.w * W1[3 * 64 + lane];
            acc += c2.x * W1[4 * 64 + lane] + c2.y * W1[5 * 64 + lane]
                 + c2.z * W1[6 * 64 + lane] + c2.w * W1[7 * 64 + lane];
            #pragma unroll
            for (int c = 0; c < 16; ++c)
                acc += __shfl(attv, c, 64) * W1[(8 + c) * 64 + lane];
            a1 = ftanh(acc);
        }

        // ---- layer 2: act2[lane] = tanh(act1 . W2[:,lane] + B2[lane]) ----
        float a2;
        {
            float acc = B2[lane];
            #pragma unroll
            for (int c = 0; c < 64; ++c)
                acc += __shfl(a1, c, 64) * W2[c * 64 + lane];
            a2 = ftanh(acc);
        }

        // ---- layer 3: out[lane&31] = tanh(act2 . Wt[:,lane&31] + Bt[lane&31]) ----
        {
            const int j = lane & 31;
            float acc = Bt[j];
            #pragma unroll
            for (int c = 0; c < 64; ++c)
                acc += __shfl(a2, c, 64) * Wt[c * 32 + j];
            if (lane < 32) out[(size_t)n * 32 + lane] = ftanh(acc);
        }
    }
}

extern "C" void kernel_launch(void* const* d_in, const int* in_sizes, int n_in,
                              void* d_out, int out_size, void* d_ws, size_t ws_size,
                              hipStream_t stream) {
    (void)in_sizes; (void)n_in; (void)out_size; (void)d_ws; (void)ws_size;
    attn_mlp_fused<<<1024, 256, 0, stream>>>(
        (const float*)d_in[0],  (const float*)d_in[1],
        (const float*)d_in[2],  (const float*)d_in[3],
        d_in[4],
        (const float*)d_in[5],  (const float*)d_in[6],
        (const float*)d_in[7],  (const float*)d_in[8],
        (const float*)d_in[9],  (const float*)d_in[10],
        (const float*)d_in[11], (const float*)d_in[12],
        (const float*)d_in[13], (const float*)d_in[14],
        (const float*)d_in[15], (const float*)d_in[16],
        (const float*)d_in[17], (const float*)d_in[18],
        (float*)d_out);
}

// Round 6
// 92.043 us; speedup vs baseline: 3.7405x; 3.7405x over previous
//
#include <hip/hip_runtime.h>
#include <cstdint>

// Problem constants: N=8192, T=1024, CD=4, H=2, KD=VD=8, DA=8, AOD=16, LAT=64, OUT=32.
//
// History: R1-R5 all showed 33-425 MB of scratch-class WRITE_SIZE at
// VGPR_Count=64 regardless of launch bounds / waves_per_eu / array->scalar
// rewrites. The monolithic kernel's long tail keeps enough state live that
// the allocator spills the streaming loop. This round SPLITS the op:
//   phase 1: streaming attention -> attn[8192,16] into d_ws (512 KB).
//            Live set ~22 regs; one row per wave; no tail.
//   phase 2: Wo/exp + 3-layer tanh MLP from d_ws -> out. Tiny.
// If phase 1 STILL shows >100MB WRITE_SIZE, the spill theory is refuted.

__device__ __forceinline__ float bflo(uint32_t u) { return __uint_as_float(u << 16); }
__device__ __forceinline__ float bfhi(uint32_t u) { return __uint_as_float(u & 0xFFFF0000u); }
__device__ __forceinline__ uint32_t f2bf(float f) {
    uint32_t x = __float_as_uint(f);
    return (x + 0x7FFFu + ((x >> 16) & 1u)) >> 16;   // RNE
}
__device__ __forceinline__ float ftanh(float x) {
    float e = __expf(2.0f * x);
    return 1.0f - 2.0f / (e + 1.0f);   // stable for +-inf of e
}

// ---------------- phase 1: masked attention -> attn[n,16] ----------------
__global__ void attn_phase1(const float* __restrict__ coord1,
                            const float* __restrict__ att_coeff,
                            const float* __restrict__ local_coords,
                            const void*  __restrict__ maskp,
                            const float* __restrict__ Wq, const float* __restrict__ Bq,
                            const float* __restrict__ Wk, const float* __restrict__ Bk,
                            const float* __restrict__ Wv, const float* __restrict__ Bv,
                            float* __restrict__ ws)
{
    __shared__ uint4 vq[2048];                 // v table, bf16x2 packed, swizzled (32 KB)

    const int tid  = threadIdx.x;
    const int lane = tid & 63;
    const int wid  = tid >> 6;

    // mask element size: 4-byte (int/float 0/1) vs 1-byte (bool)
    uint4 mm = ((const uint4*)maskp)[tid];
    bool ok = (mm.x <= 1u || mm.x == 0x3F800000u) &&
              (mm.y <= 1u || mm.y == 0x3F800000u) &&
              (mm.z <= 1u || mm.z == 0x3F800000u) &&
              (mm.w <= 1u || mm.w == 0x3F800000u);
    const bool m4 = (__all(ok) != 0);

    // stage v = att_coeff @ Wv + Bv (bf16x2, XOR-swizzled)
    #pragma unroll
    for (int tt = 0; tt < 4; ++tt) {
        const int t = tid * 4 + tt;
        const float4 a0 = *(const float4*)(att_coeff + t * 8);
        const float4 a1 = *(const float4*)(att_coeff + t * 8 + 4);
        float vr[16];
        #pragma unroll
        for (int o = 0; o < 16; ++o) {
            vr[o] = Bv[o]
                + a0.x * Wv[o]      + a0.y * Wv[16 + o] + a0.z * Wv[32 + o] + a0.w * Wv[48 + o]
                + a1.x * Wv[64 + o] + a1.y * Wv[80 + o] + a1.z * Wv[96 + o] + a1.w * Wv[112 + o];
        }
        #pragma unroll
        for (int h = 0; h < 2; ++h) {
            const int g  = 2 * t + h;
            const int gs = (g & ~7) | ((g ^ (g >> 3)) & 7);
            uint4 pk;
            pk.x = f2bf(vr[h * 8 + 0]) | (f2bf(vr[h * 8 + 1]) << 16);
            pk.y = f2bf(vr[h * 8 + 2]) | (f2bf(vr[h * 8 + 3]) << 16);
            pk.z = f2bf(vr[h * 8 + 4]) | (f2bf(vr[h * 8 + 5]) << 16);
            pk.w = f2bf(vr[h * 8 + 6]) | (f2bf(vr[h * 8 + 7]) << 16);
            vq[gs] = pk;
        }
    }
    __syncthreads();

    const int l  = lane & 31;          // t-slot within half-wave
    const int hb = (lane >> 5) * 8;    // own head base (0 or 8)
    const int g0 = 2 * l + (lane >> 5);
    const int bg = (g0 & ~7) | ((g0 ^ (g0 >> 3)) & 7);   // vq[bg + 64*i]
    const float rs8 = 0.35355339059327373f;              // 1/sqrt(KD)

    const uint32_t msh   = m4 ? 0u : ((l & 3) * 8);
    const uint32_t mmsk  = m4 ? 0xFFFFFFFFu : 0xFFu;
    const int      mstep = m4 ? 32 : 8;

    const int n = (blockIdx.x << 2) + wid;     // one row per wave

    // own-head q -> folded A[4], Bs (q dead after)
    float A0, A1, A2, A3, Bsv;
    {
        const float4 c1 = *(const float4*)(coord1 + n * 4);
        float qd[8];
        #pragma unroll
        for (int d = 0; d < 8; ++d)
            qd[d] = Bq[hb + d]
                  + c1.x * Wq[0 * 16 + hb + d] + c1.y * Wq[1 * 16 + hb + d]
                  + c1.z * Wq[2 * 16 + hb + d] + c1.w * Wq[3 * 16 + hb + d];
        float a[4];
        #pragma unroll
        for (int c = 0; c < 4; ++c) {
            float s = 0.f;
            #pragma unroll
            for (int d = 0; d < 8; ++d) s += qd[d] * Wk[c * 16 + hb + d];
            a[c] = s * rs8;
        }
        float s2 = 0.f;
        #pragma unroll
        for (int d = 0; d < 8; ++d) s2 += qd[d] * Bk[hb + d];
        A0 = a[0]; A1 = a[1]; A2 = a[2]; A3 = a[3]; Bsv = s2 * rs8;
    }

    // stream own head's T-slice: t = l + 32*i
    const float4*   lcp = (const float4*)local_coords + (size_t)n * 1024 + l;
    const uint32_t* mp  = (const uint32_t*)maskp +
                          (m4 ? ((size_t)n * 1024 + l)
                              : ((size_t)n * 256 + (l >> 2)));

    float p0 = 0.f, p1 = 0.f, p2 = 0.f, p3 = 0.f;
    float p4 = 0.f, p5 = 0.f, p6 = 0.f, p7 = 0.f;
    float s0 = 0.f;

    #pragma unroll 2
    for (int i = 0; i < 32; ++i) {
        const float4   lc = lcp[i * 32];
        const uint32_t mw = mp[i * mstep];
        const bool keep = ((mw >> msh) & mmsk) != 0u;
        const float v = Bsv + lc.x * A0 + lc.y * A1 + lc.z * A2 + lc.w * A3;
        const float e = keep ? __expf(v) : 0.f;   // |v| bounded by construction: no overflow
        s0 += e;
        const uint4 w = vq[bg + (i << 6)];
        p0 += e * bflo(w.x); p1 += e * bfhi(w.x);
        p2 += e * bflo(w.y); p3 += e * bfhi(w.y);
        p4 += e * bflo(w.z); p5 += e * bfhi(w.z);
        p6 += e * bflo(w.w); p7 += e * bfhi(w.w);
    }

    // head-total sum across the half-wave
    #pragma unroll
    for (int s = 16; s; s >>= 1) s0 += __shfl_xor(s0, s, 64);

    // all-masked fallback: softmax of constant row = uniform weights
    if (s0 == 0.0f) {
        #pragma unroll 2
        for (int i = 0; i < 32; ++i) {
            const uint4 w = vq[bg + (i << 6)];
            p0 += bflo(w.x); p1 += bfhi(w.x);
            p2 += bflo(w.y); p3 += bfhi(w.y);
            p4 += bflo(w.z); p5 += bfhi(w.z);
            p6 += bflo(w.w); p7 += bfhi(w.w);
        }
        s0 = 1024.0f;
    }

    // split butterfly within half-wave: lane ends with elem (lane>>2)&7
    {
        const bool b = (lane & 16) != 0;
        const float n0 = (b ? p4 : p0) + __shfl_xor(b ? p0 : p4, 16, 64);
        const float n1 = (b ? p5 : p1) + __shfl_xor(b ? p1 : p5, 16, 64);
        const float n2 = (b ? p6 : p2) + __shfl_xor(b ? p2 : p6, 16, 64);
        const float n3 = (b ? p7 : p3) + __shfl_xor(b ? p3 : p7, 16, 64);
        p0 = n0; p1 = n1; p2 = n2; p3 = n3;
    }
    {
        const bool b = (lane & 8) != 0;
        const float n0 = (b ? p2 : p0) + __shfl_xor(b ? p0 : p2, 8, 64);
        const float n1 = (b ? p3 : p1) + __shfl_xor(b ? p1 : p3, 8, 64);
        p0 = n0; p1 = n1;
    }
    {
        const bool b = (lane & 4) != 0;
        p0 = (b ? p1 : p0) + __shfl_xor(b ? p0 : p1, 4, 64);
    }
    p0 += __shfl_xor(p0, 2, 64);
    p0 += __shfl_xor(p0, 1, 64);

    if ((lane & 3) == 0)
        ws[(size_t)n * 16 + hb + ((lane >> 2) & 7)] = p0 / s0;
}

// ---------------- phase 2: Wo/exp + tanh MLP ----------------
__global__ void attn_phase2(const float* __restrict__ coord1,
                            const float* __restrict__ coord2,
                            const float* __restrict__ ws,
                            const float* __restrict__ Wo, const float* __restrict__ Bo,
                            const float* __restrict__ W1, const float* __restrict__ B1,
                            const float* __restrict__ W2, const float* __restrict__ B2,
                            const float* __restrict__ Wt, const float* __restrict__ Bt,
                            float* __restrict__ out)
{
    const int lane = threadIdx.x & 63;
    const int wid  = threadIdx.x >> 6;
    const int n    = (blockIdx.x << 2) + wid;  // one row per wave

    const float4 c1 = *(const float4*)(coord1 + n * 4);
    const float4 c2 = *(const float4*)(coord2 + n * 4);
    const float  av = ws[(size_t)n * 16 + (lane & 15)];   // lane c<16 holds attn[c]

    // att[j] = exp(-(attn . Wo[:,j] + Bo[j])), j = lane&15
    float attv;
    {
        const int j = lane & 15;
        float acc = Bo[j];
        #pragma unroll
        for (int c = 0; c < 16; ++c)
            acc += __shfl(av, c, 64) * Wo[c * 16 + j];
        attv = __expf(-acc);
    }

    // layer 1: act1[lane] = tanh([c1,c2,att] . W1[:,lane] + B1[lane])
    float a1;
    {
        float acc = B1[lane];
        acc += c1.x * W1[0 * 64 + lane] + c1.y * W1[1 * 64 + lane]
             + c1.z * W1[2 * 64 + lane] + c1.w * W1[3 * 64 + lane];
        acc += c2.x * W1[4 * 64 + lane] + c2.y * W1[5 * 64 + lane]
             + c2.z * W1[6 * 64 + lane] + c2.w * W1[7 * 64 + lane];
        #pragma unroll
        for (int c = 0; c < 16; ++c)
            acc += __shfl(attv, c, 64) * W1[(8 + c) * 64 + lane];
        a1 = ftanh(acc);
    }

    // layer 2: act2[lane] = tanh(act1 . W2[:,lane] + B2[lane])
    float a2;
    {
        float acc = B2[lane];
        #pragma unroll
        for (int c = 0; c < 64; ++c)
            acc += __shfl(a1, c, 64) * W2[c * 64 + lane];
        a2 = ftanh(acc);
    }

    // layer 3: out[lane&31] = tanh(act2 . Wt[:,lane&31] + Bt[lane&31])
    {
        const int j = lane & 31;
        float acc = Bt[j];
        #pragma unroll
        for (int c = 0; c < 64; ++c)
            acc += __shfl(a2, c, 64) * Wt[c * 32 + j];
        if (lane < 32) out[(size_t)n * 32 + lane] = ftanh(acc);
    }
}

extern "C" void kernel_launch(void* const* d_in, const int* in_sizes, int n_in,
                              void* d_out, int out_size, void* d_ws, size_t ws_size,
                              hipStream_t stream) {
    (void)in_sizes; (void)n_in; (void)out_size; (void)ws_size;
    float* ws = (float*)d_ws;   // 8192*16 floats = 512 KB
    attn_phase1<<<2048, 256, 0, stream>>>(
        (const float*)d_in[0],  (const float*)d_in[2],
        (const float*)d_in[3],  d_in[4],
        (const float*)d_in[5],  (const float*)d_in[6],
        (const float*)d_in[7],  (const float*)d_in[8],
        (const float*)d_in[9],  (const float*)d_in[10],
        ws);
    attn_phase2<<<2048, 256, 0, stream>>>(
        (const float*)d_in[0],  (const float*)d_in[1],
        ws,
        (const float*)d_in[11], (const float*)d_in[12],
        (const float*)d_in[13], (const float*)d_in[14],
        (const float*)d_in[15], (const float*)d_in[16],
        (const float*)d_in[17], (const float*)d_in[18],
        (float*)d_out);
}